// Round 11
// baseline (15.232 us; speedup 1.0000x reference)
//
#include <hip/hip_runtime.h>

#define IMG 256
#define NPIX (IMG*IMG)
#define NFACES 512
#define TILE 8
#define NTX (IMG/TILE)           // 32 tiles per dim
#define TILE_NDC (2.0f*TILE/IMG) // 0.0625
#define NW 8                     // waves per block
#define MAXREC 128               // LDS record slots per chunk
#define D_MARGIN2 0.01f          // (0.10)^2 : alpha-cull margin, sigmoid(-10)=4.5e-5
#define SCORE_DELTA 12.0f        // e^-12 weight-ratio cull for rgb path

__device__ __forceinline__ float clamp01(float x){ return fminf(fmaxf(x, 0.0f), 1.0f); }

// Build one 36-float face record from global vertex/texture data.
__device__ __forceinline__ void build_rec(const float* __restrict__ v,
                                          const float* __restrict__ t,
                                          float* __restrict__ dst)
{
    float x0 = v[0], y0 = v[1], z0 = v[2];
    float x1 = v[3], y1 = v[4], z1 = v[5];
    float x2 = v[6], y2 = v[7], z2 = v[8];
    float u0=t[0], u1=t[1], u2=t[2], u3=t[3], u4=t[4];
    float u5=t[5], u6=t[6], u7=t[7], u8=t[8];
    float den = (y1 - y2) * (x0 - x2) + (x2 - x1) * (y0 - y2);
    if (fabsf(den) < 1e-10f) den = 1e-10f;
    float invden = 1.0f / den;
    float a0 = (y1 - y2) * invden, b0 = (x2 - x1) * invden;
    float c0 = -(a0 * x2 + b0 * y2);
    float a1 = (y2 - y0) * invden, b1 = (x0 - x2) * invden;
    float c1 = -(a1 * x2 + b1 * y2);
    float dx0 = x1 - x0, dy0 = y1 - y0;
    float dx1 = x2 - x1, dy1 = y2 - y1;
    float dx2 = x0 - x2, dy2 = y0 - y2;
    float il0 = 1.0f / fmaxf(dx0*dx0 + dy0*dy0, 1e-12f);
    float il1 = 1.0f / fmaxf(dx1*dx1 + dy1*dy1, 1e-12f);
    float il2 = 1.0f / fmaxf(dx2*dx2 + dy2*dy2, 1e-12f);
    float4* rw = (float4*)dst;
    rw[0] = make_float4(a0, b0, c0, a1);
    rw[1] = make_float4(b1, c1, x0, y0);
    rw[2] = make_float4(x1, y1, x2, y2);
    rw[3] = make_float4(dx0, dy0, dx1, dy1);
    rw[4] = make_float4(dx2, dy2, il0, il1);
    rw[5] = make_float4(il2, 1.0f/z0, 1.0f/z1, 1.0f/z2);
    rw[6] = make_float4(u0, u1, u2, u3);
    rw[7] = make_float4(u4, u5, u6, u7);
    rw[8] = make_float4(u8, 0.0f, 0.0f, 0.0f);
}

// One kernel: per-tile cull, survivor records in LDS, online-softmax raster.
// Block = 512 threads = 8 waves, one 8x8-pixel tile (lane = pixel).
__global__ __launch_bounds__(512) void mr_raster(const float* __restrict__ fv,
                                                 const float* __restrict__ ft,
                                                 float* __restrict__ out)
{
    __shared__ unsigned int list[NFACES];
    __shared__ __align__(16) float recs[MAXREC * 36];
    __shared__ float parts[NW][64][6];
    __shared__ float Lred[NW];
    __shared__ int wcnt[NW];

    const int tid  = threadIdx.x;
    const int lane = tid & 63;
    const int wave = tid >> 6;
    const int tx = blockIdx.x & (NTX - 1);
    const int ty = blockIdx.x >> 5;

    const float txmin = tx * TILE_NDC - 1.0f;
    const float txmax = txmin + TILE_NDC;
    const float tymin = ty * TILE_NDC - 1.0f;
    const float tymax = tymin + TILE_NDC;

    // ---- phase 1: per-face cull quantities (1 face / thread) ----
    float d2g, schi;
    {
        const float* vp = fv + tid * 9;
        float x0 = vp[0], y0 = vp[1], z0 = vp[2];
        float x1 = vp[3], y1 = vp[4], z1 = vp[5];
        float x2 = vp[6], y2 = vp[7], z2 = vp[8];
        float xmn = fminf(x0, fminf(x1, x2)), xmx = fmaxf(x0, fmaxf(x1, x2));
        float ymn = fminf(y0, fminf(y1, y2)), ymx = fmaxf(y0, fmaxf(y1, y2));
        float zmn = fminf(z0, fminf(z1, z2)), zmx = fmaxf(z0, fmaxf(z1, z2));
        float gx = fmaxf(0.0f, fmaxf(txmin - xmx, xmn - txmax));
        float gy = fmaxf(0.0f, fmaxf(tymin - ymx, ymn - tymax));
        d2g  = gx * gx + gy * gy;
        schi = (100.0f - zmn) * (1000.0f/99.0f);
        float sclo = (100.0f - zmx) * (1000.0f/99.0f);
        // achievable-score lower bound: L1 distance upper bound to vertex 0
        float mx = fmaxf(x0 - txmin, txmax - x0);
        float my = fmaxf(y0 - tymin, tymax - y0);
        float Lpart = fmaf(mx + my, -100.0f, sclo);
        #pragma unroll
        for (int off = 32; off; off >>= 1)
            Lpart = fmaxf(Lpart, __shfl_xor(Lpart, off, 64));
        if (lane == 0) Lred[wave] = Lpart;
    }
    __syncthreads();
    float Lcut = Lred[0];
    #pragma unroll
    for (int k = 1; k < NW; ++k) Lcut = fmaxf(Lcut, Lred[k]);
    Lcut -= SCORE_DELTA;

    // ---- phase 2: deterministic compact + fused own-face record build ----
    int n;
    {
        const float tq = (schi - Lcut) * 0.01f;
        const float thr = fmaxf(D_MARGIN2, tq > 0.0f ? tq * tq : 0.0f);
        const bool keep = d2g <= thr;
        const unsigned long long mask = __ballot(keep);
        const int pre = __builtin_amdgcn_mbcnt_hi((unsigned)(mask >> 32),
                        __builtin_amdgcn_mbcnt_lo((unsigned)mask, 0));
        if (lane == 0) wcnt[wave] = (int)__popcll(mask);
        __syncthreads();                    // wcnt ready
        int base = 0;
        n = 0;
        #pragma unroll
        for (int k = 0; k < NW; ++k) {
            int c = wcnt[k];
            if (k < wave) base += c;
            n += c;
        }
        if (keep) {
            const int dst = base + pre;
            list[dst] = (unsigned)tid;      // needed only for overflow chunks
            if (dst < MAXREC)               // build own face straight into LDS
                build_rec(fv + tid * 9, ft + tid * 9, &recs[dst * 36]);
        }
    }
    __syncthreads();                        // recs + list ready

    // ---- phase 3: evaluation (wave w takes j = w, w+8, ...) ----
    const int w = tx * TILE + (lane & 7);
    const int h = ty * TILE + (lane >> 3);
    const float px = (w + 0.5f) * (2.0f / IMG) - 1.0f;
    const float py = (h + 0.5f) * (2.0f / IMG) - 1.0f;

    float m = 1.0f;            // running max in zn*1000 units; init EPS/GAMMA = 1
    float dsum = 0.0f, r0 = 0.0f, r1 = 0.0f, r2 = 0.0f, pprod = 1.0f;

    for (int cb = 0; cb < n; cb += MAXREC) {
        const int cn = min(n - cb, MAXREC);
        if (cb) {                           // overflow chunks: rebuild from list
            __syncthreads();
            if (tid < cn) {
                const int fi = (int)list[cb + tid];
                build_rec(fv + fi * 9, ft + fi * 9, &recs[tid * 36]);
            }
            __syncthreads();
        }

        for (int j = wave; j < cn; j += NW) {
            const float* rp = &recs[j * 36];
            const float4 v0 = *(const float4*)(rp +  0);
            const float4 v1 = *(const float4*)(rp +  4);
            const float4 v2 = *(const float4*)(rp +  8);
            const float4 v3 = *(const float4*)(rp + 12);
            const float4 v4 = *(const float4*)(rp + 16);
            const float4 v5 = *(const float4*)(rp + 20);

            float w0 = fmaf(v0.x, px, fmaf(v0.y, py, v0.z));
            float w1 = fmaf(v0.w, px, fmaf(v1.x, py, v1.y));
            float w2 = 1.0f - w0 - w1;
            bool inside = (w0 >= 0.0f) && (w1 >= 0.0f) && (w2 >= 0.0f);

            float rx0 = px - v1.z, ry0 = py - v1.w;
            float t0 = clamp01((rx0 * v3.x + ry0 * v3.y) * v4.z);
            float ux0 = rx0 - t0 * v3.x, uy0 = ry0 - t0 * v3.y;
            float d2 = ux0 * ux0 + uy0 * uy0;

            float rx1 = px - v2.x, ry1 = py - v2.y;
            float t1 = clamp01((rx1 * v3.z + ry1 * v3.w) * v4.w);
            float ux1 = rx1 - t1 * v3.z, uy1 = ry1 - t1 * v3.w;
            d2 = fminf(d2, ux1 * ux1 + uy1 * uy1);

            float rx2 = px - v2.z, ry2 = py - v2.w;
            float t2 = clamp01((rx2 * v4.x + ry2 * v4.y) * v5.x);
            float ux2 = rx2 - t2 * v4.x, uy2 = ry2 - t2 * v4.y;
            d2 = fminf(d2, ux2 * ux2 + uy2 * uy2);

            float dist = sqrtf(d2 + 1e-12f);
            // overflow-safe sigmoid: et = exp(-100*dist) in (0,1]
            float et = __expf(-100.0f * dist);
            float rr = __builtin_amdgcn_rcpf(1.0f + et);
            float prob = inside ? rr : et * rr;      // sigmoid(sgn*dist/SIGMA)
            float omp  = inside ? et * rr : rr;      // 1 - prob, never inf*0

            // valid==1 always (z in [1.5,90.5]); s >= 1/3 (weights sum to 1)
            float wc0 = clamp01(w0), wc1 = clamp01(w1), wc2 = clamp01(w2);
            float s    = wc0 + wc1 + wc2;
            float invs = __builtin_amdgcn_rcpf(s);
            float q    = fmaf(wc0, v5.y, fmaf(wc1, v5.z, wc2 * v5.w));
            float zp   = s * __builtin_amdgcn_rcpf(q);
            float zs   = fmaf(zp, -10.1010103f, 1010.10101f); // (100-zp)*(1000/99)

            // single-exp online softmax update
            float d  = zs - m;
            float e  = __expf(-fabsf(d));
            bool  up = d > 0.0f;
            float sc = up ? e : 1.0f;
            float pe = up ? 1.0f : e;
            m = fmaxf(m, zs);
            float we = prob * pe;

            const float4 v6 = *(const float4*)(rp + 24);
            const float4 v7 = *(const float4*)(rp + 28);
            const float4 v8 = *(const float4*)(rp + 32);
            float cq0 = fmaf(wc0, v6.x, fmaf(wc1, v6.w, wc2 * v7.z));
            float cq1 = fmaf(wc0, v6.y, fmaf(wc1, v7.x, wc2 * v7.w));
            float cq2 = fmaf(wc0, v6.z, fmaf(wc1, v7.y, wc2 * v8.x));
            float wei = we * invs;

            dsum = fmaf(dsum, sc, we);
            r0 = fmaf(r0, sc, wei * cq0);
            r1 = fmaf(r1, sc, wei * cq1);
            r2 = fmaf(r2, sc, wei * cq2);
            pprod *= omp;
        }
    }

    parts[wave][lane][0] = m;
    parts[wave][lane][1] = dsum;
    parts[wave][lane][2] = r0;
    parts[wave][lane][3] = r1;
    parts[wave][lane][4] = r2;
    parts[wave][lane][5] = pprod;
    __syncthreads();

    if (tid < 64) {
        float M = parts[0][tid][0];
        #pragma unroll
        for (int k = 1; k < NW; ++k) M = fmaxf(M, parts[k][tid][0]);
        float ds = 0.0f, R0 = 0.0f, R1 = 0.0f, R2 = 0.0f, pp = 1.0f;
        #pragma unroll
        for (int k = 0; k < NW; ++k) {
            float sk = __expf(parts[k][tid][0] - M);
            ds = fmaf(parts[k][tid][1], sk, ds);
            R0 = fmaf(parts[k][tid][2], sk, R0);
            R1 = fmaf(parts[k][tid][3], sk, R1);
            R2 = fmaf(parts[k][tid][4], sk, R2);
            pp *= parts[k][tid][5];
        }
        ds += __expf(1.0f - M);                 // wbg, EPS/GAMMA = 1
        float inv = __builtin_amdgcn_rcpf(ds);
        const int ww = tx * TILE + (tid & 7);
        const int hh = ty * TILE + (tid >> 3);
        const int p = hh * IMG + ww;
        out[p]          = R0 * inv;
        out[NPIX + p]   = R1 * inv;
        out[2*NPIX + p] = R2 * inv;
        out[3*NPIX + p] = 1.0f - pp;
    }
}

extern "C" void kernel_launch(void* const* d_in, const int* in_sizes, int n_in,
                              void* d_out, int out_size, void* d_ws, size_t ws_size,
                              hipStream_t stream) {
    const float* fv = (const float*)d_in[0];
    const float* ft = (const float*)d_in[1];
    float* out = (float*)d_out;

    mr_raster<<<(IMG/TILE)*(IMG/TILE), 512, 0, stream>>>(fv, ft, out);
}

// Round 12
// 14.102 us; speedup vs baseline: 1.0801x; 1.0801x over previous
//
#include <hip/hip_runtime.h>

#define IMG 256
#define NPIX (IMG*IMG)
#define NFACES 512
#define TILE 8
#define NTX (IMG/TILE)           // 32 tiles per dim
#define TILE_NDC (2.0f*TILE/IMG) // 0.0625
#define NW 4                     // waves per block (256 threads)
#define MAXREC 128               // LDS record slots per chunk
#define D_MARGIN2 0.01f          // (0.10)^2 : alpha-cull margin, sigmoid(-10)=4.5e-5
#define SCORE_DELTA 12.0f        // e^-12 weight-ratio cull for rgb path

__device__ __forceinline__ float clamp01(float x){ return fminf(fmaxf(x, 0.0f), 1.0f); }

// Build one 36-float face record from global vertex/texture data.
__device__ __forceinline__ void build_rec(const float* __restrict__ v,
                                          const float* __restrict__ t,
                                          float* __restrict__ dst)
{
    float x0 = v[0], y0 = v[1], z0 = v[2];
    float x1 = v[3], y1 = v[4], z1 = v[5];
    float x2 = v[6], y2 = v[7], z2 = v[8];
    float u0=t[0], u1=t[1], u2=t[2], u3=t[3], u4=t[4];
    float u5=t[5], u6=t[6], u7=t[7], u8=t[8];
    float den = (y1 - y2) * (x0 - x2) + (x2 - x1) * (y0 - y2);
    if (fabsf(den) < 1e-10f) den = 1e-10f;
    float invden = 1.0f / den;
    float a0 = (y1 - y2) * invden, b0 = (x2 - x1) * invden;
    float c0 = -(a0 * x2 + b0 * y2);
    float a1 = (y2 - y0) * invden, b1 = (x0 - x2) * invden;
    float c1 = -(a1 * x2 + b1 * y2);
    float dx0 = x1 - x0, dy0 = y1 - y0;
    float dx1 = x2 - x1, dy1 = y2 - y1;
    float dx2 = x0 - x2, dy2 = y0 - y2;
    float il0 = 1.0f / fmaxf(dx0*dx0 + dy0*dy0, 1e-12f);
    float il1 = 1.0f / fmaxf(dx1*dx1 + dy1*dy1, 1e-12f);
    float il2 = 1.0f / fmaxf(dx2*dx2 + dy2*dy2, 1e-12f);
    float4* rw = (float4*)dst;
    rw[0] = make_float4(a0, b0, c0, a1);
    rw[1] = make_float4(b1, c1, x0, y0);
    rw[2] = make_float4(x1, y1, x2, y2);
    rw[3] = make_float4(dx0, dy0, dx1, dy1);
    rw[4] = make_float4(dx2, dy2, il0, il1);
    rw[5] = make_float4(il2, 1.0f/z0, 1.0f/z1, 1.0f/z2);
    rw[6] = make_float4(u0, u1, u2, u3);
    rw[7] = make_float4(u4, u5, u6, u7);
    rw[8] = make_float4(u8, 0.0f, 0.0f, 0.0f);
}

// One kernel: per-tile cull, survivor records in LDS, online-softmax raster.
// Block = 256 threads = 4 waves, one 8x8-pixel tile (lane = pixel).
// Smaller blocks -> 5+ resident blocks/CU -> whole 1024-block grid co-resident.
__global__ __launch_bounds__(256) void mr_raster(const float* __restrict__ fv,
                                                 const float* __restrict__ ft,
                                                 float* __restrict__ out)
{
    __shared__ unsigned int list[NFACES];
    __shared__ __align__(16) float recs[MAXREC * 36];
    __shared__ float parts[NW][64][6];
    __shared__ float Lred[NW];
    __shared__ int wcnt[2 * NW];            // 2 ballot rounds x 4 waves

    const int tid  = threadIdx.x;
    const int lane = tid & 63;
    const int wave = tid >> 6;
    const int tx = blockIdx.x & (NTX - 1);
    const int ty = blockIdx.x >> 5;

    const float txmin = tx * TILE_NDC - 1.0f;
    const float txmax = txmin + TILE_NDC;
    const float tymin = ty * TILE_NDC - 1.0f;
    const float tymax = tymin + TILE_NDC;

    // ---- phase 1: per-face cull quantities (2 faces / thread) ----
    float d2g[2], schi[2];
    {
        float Lpart = -3e38f;
        #pragma unroll
        for (int r = 0; r < 2; ++r) {
            const int f = (r << 8) + tid;
            const float* vp = fv + f * 9;
            float x0 = vp[0], y0 = vp[1], z0 = vp[2];
            float x1 = vp[3], y1 = vp[4], z1 = vp[5];
            float x2 = vp[6], y2 = vp[7], z2 = vp[8];
            float xmn = fminf(x0, fminf(x1, x2)), xmx = fmaxf(x0, fmaxf(x1, x2));
            float ymn = fminf(y0, fminf(y1, y2)), ymx = fmaxf(y0, fmaxf(y1, y2));
            float zmn = fminf(z0, fminf(z1, z2)), zmx = fmaxf(z0, fmaxf(z1, z2));
            float gx = fmaxf(0.0f, fmaxf(txmin - xmx, xmn - txmax));
            float gy = fmaxf(0.0f, fmaxf(tymin - ymx, ymn - tymax));
            d2g[r]  = gx * gx + gy * gy;
            schi[r] = (100.0f - zmn) * (1000.0f/99.0f);
            float sclo = (100.0f - zmx) * (1000.0f/99.0f);
            float mx = fmaxf(x0 - txmin, txmax - x0);
            float my = fmaxf(y0 - tymin, tymax - y0);
            Lpart = fmaxf(Lpart, fmaf(mx + my, -100.0f, sclo));
        }
        #pragma unroll
        for (int off = 32; off; off >>= 1)
            Lpart = fmaxf(Lpart, __shfl_xor(Lpart, off, 64));
        if (lane == 0) Lred[wave] = Lpart;
    }
    __syncthreads();
    float Lcut = Lred[0];
    #pragma unroll
    for (int k = 1; k < NW; ++k) Lcut = fmaxf(Lcut, Lred[k]);
    Lcut -= SCORE_DELTA;

    // ---- phase 2: deterministic two-round ballot-compact (no atomics) ----
    bool keep[2];
    int pre[2];
    #pragma unroll
    for (int r = 0; r < 2; ++r) {
        const float tq = (schi[r] - Lcut) * 0.01f;
        const float thr = fmaxf(D_MARGIN2, tq > 0.0f ? tq * tq : 0.0f);
        keep[r] = d2g[r] <= thr;
        const unsigned long long mask = __ballot(keep[r]);
        pre[r] = __builtin_amdgcn_mbcnt_hi((unsigned)(mask >> 32),
                 __builtin_amdgcn_mbcnt_lo((unsigned)mask, 0));
        if (lane == 0) wcnt[r * NW + wave] = (int)__popcll(mask);
    }
    __syncthreads();
    int n = 0;
    int base[2];
    {
        #pragma unroll
        for (int r = 0; r < 2; ++r) {
            const int g = r * NW + wave;
            int b = 0;
            #pragma unroll
            for (int k = 0; k < 2 * NW; ++k) {
                int c = wcnt[k];
                if (k < g) b += c;
                n += c;
            }
            base[r] = b;
        }
        n >>= 1;                        // each wcnt summed twice above
        #pragma unroll
        for (int r = 0; r < 2; ++r)
            if (keep[r]) list[base[r] + pre[r]] = (unsigned)((r << 8) + tid);
    }
    __syncthreads();

    // ---- phase 3: chunked dense record build (LDS) + evaluation ----
    const int w = tx * TILE + (lane & 7);
    const int h = ty * TILE + (lane >> 3);
    const float px = (w + 0.5f) * (2.0f / IMG) - 1.0f;
    const float py = (h + 0.5f) * (2.0f / IMG) - 1.0f;

    float m = 1.0f;            // running max in zn*1000 units; init EPS/GAMMA = 1
    float dsum = 0.0f, r0 = 0.0f, r1 = 0.0f, r2 = 0.0f, pprod = 1.0f;

    for (int cb = 0; cb < n; cb += MAXREC) {
        const int cn = min(n - cb, MAXREC);
        if (cb) __syncthreads();          // recs reuse across chunks
        if (tid < cn) {
            const int fi = (int)list[cb + tid];
            build_rec(fv + fi * 9, ft + fi * 9, &recs[tid * 36]);
        }
        __syncthreads();

        for (int j = wave; j < cn; j += NW) {
            const float* rp = &recs[j * 36];
            const float4 v0 = *(const float4*)(rp +  0);
            const float4 v1 = *(const float4*)(rp +  4);
            const float4 v2 = *(const float4*)(rp +  8);
            const float4 v3 = *(const float4*)(rp + 12);
            const float4 v4 = *(const float4*)(rp + 16);
            const float4 v5 = *(const float4*)(rp + 20);

            float w0 = fmaf(v0.x, px, fmaf(v0.y, py, v0.z));
            float w1 = fmaf(v0.w, px, fmaf(v1.x, py, v1.y));
            float w2 = 1.0f - w0 - w1;
            bool inside = (w0 >= 0.0f) && (w1 >= 0.0f) && (w2 >= 0.0f);

            float rx0 = px - v1.z, ry0 = py - v1.w;
            float t0 = clamp01((rx0 * v3.x + ry0 * v3.y) * v4.z);
            float ux0 = rx0 - t0 * v3.x, uy0 = ry0 - t0 * v3.y;
            float d2 = ux0 * ux0 + uy0 * uy0;

            float rx1 = px - v2.x, ry1 = py - v2.y;
            float t1 = clamp01((rx1 * v3.z + ry1 * v3.w) * v4.w);
            float ux1 = rx1 - t1 * v3.z, uy1 = ry1 - t1 * v3.w;
            d2 = fminf(d2, ux1 * ux1 + uy1 * uy1);

            float rx2 = px - v2.z, ry2 = py - v2.w;
            float t2 = clamp01((rx2 * v4.x + ry2 * v4.y) * v5.x);
            float ux2 = rx2 - t2 * v4.x, uy2 = ry2 - t2 * v4.y;
            d2 = fminf(d2, ux2 * ux2 + uy2 * uy2);

            float dist = sqrtf(d2 + 1e-12f);
            // overflow-safe sigmoid: et = exp(-100*dist) in (0,1]
            float et = __expf(-100.0f * dist);
            float rr = __builtin_amdgcn_rcpf(1.0f + et);
            float prob = inside ? rr : et * rr;      // sigmoid(sgn*dist/SIGMA)
            float omp  = inside ? et * rr : rr;      // 1 - prob, never inf*0

            // valid==1 always (z in [1.5,90.5]); s >= 1/3 (weights sum to 1)
            float wc0 = clamp01(w0), wc1 = clamp01(w1), wc2 = clamp01(w2);
            float s    = wc0 + wc1 + wc2;
            float invs = __builtin_amdgcn_rcpf(s);
            float q    = fmaf(wc0, v5.y, fmaf(wc1, v5.z, wc2 * v5.w));
            float zp   = s * __builtin_amdgcn_rcpf(q);
            float zs   = fmaf(zp, -10.1010103f, 1010.10101f); // (100-zp)*(1000/99)

            // single-exp online softmax update
            float d  = zs - m;
            float e  = __expf(-fabsf(d));
            bool  up = d > 0.0f;
            float sc = up ? e : 1.0f;
            float pe = up ? 1.0f : e;
            m = fmaxf(m, zs);
            float we = prob * pe;

            const float4 v6 = *(const float4*)(rp + 24);
            const float4 v7 = *(const float4*)(rp + 28);
            const float4 v8 = *(const float4*)(rp + 32);
            float cq0 = fmaf(wc0, v6.x, fmaf(wc1, v6.w, wc2 * v7.z));
            float cq1 = fmaf(wc0, v6.y, fmaf(wc1, v7.x, wc2 * v7.w));
            float cq2 = fmaf(wc0, v6.z, fmaf(wc1, v7.y, wc2 * v8.x));
            float wei = we * invs;

            dsum = fmaf(dsum, sc, we);
            r0 = fmaf(r0, sc, wei * cq0);
            r1 = fmaf(r1, sc, wei * cq1);
            r2 = fmaf(r2, sc, wei * cq2);
            pprod *= omp;
        }
    }

    parts[wave][lane][0] = m;
    parts[wave][lane][1] = dsum;
    parts[wave][lane][2] = r0;
    parts[wave][lane][3] = r1;
    parts[wave][lane][4] = r2;
    parts[wave][lane][5] = pprod;
    __syncthreads();

    if (tid < 64) {
        float M = parts[0][tid][0];
        #pragma unroll
        for (int k = 1; k < NW; ++k) M = fmaxf(M, parts[k][tid][0]);
        float ds = 0.0f, R0 = 0.0f, R1 = 0.0f, R2 = 0.0f, pp = 1.0f;
        #pragma unroll
        for (int k = 0; k < NW; ++k) {
            float sk = __expf(parts[k][tid][0] - M);
            ds = fmaf(parts[k][tid][1], sk, ds);
            R0 = fmaf(parts[k][tid][2], sk, R0);
            R1 = fmaf(parts[k][tid][3], sk, R1);
            R2 = fmaf(parts[k][tid][4], sk, R2);
            pp *= parts[k][tid][5];
        }
        ds += __expf(1.0f - M);                 // wbg, EPS/GAMMA = 1
        float inv = __builtin_amdgcn_rcpf(ds);
        const int ww = tx * TILE + (tid & 7);
        const int hh = ty * TILE + (tid >> 3);
        const int p = hh * IMG + ww;
        out[p]          = R0 * inv;
        out[NPIX + p]   = R1 * inv;
        out[2*NPIX + p] = R2 * inv;
        out[3*NPIX + p] = 1.0f - pp;
    }
}

extern "C" void kernel_launch(void* const* d_in, const int* in_sizes, int n_in,
                              void* d_out, int out_size, void* d_ws, size_t ws_size,
                              hipStream_t stream) {
    const float* fv = (const float*)d_in[0];
    const float* ft = (const float*)d_in[1];
    float* out = (float*)d_out;

    mr_raster<<<(IMG/TILE)*(IMG/TILE), 256, 0, stream>>>(fv, ft, out);
}